// Round 5
// baseline (1986.405 us; speedup 1.0000x reference)
//
#include <hip/hip_runtime.h>
#include <hip/hip_fp16.h>

typedef unsigned int u32;
typedef _Float16 h2v __attribute__((ext_vector_type(2)));

#define B_ 64
#define T_ 1024
#define H_ 512
#define I_ 512

// ---------------- fp16 dot2 helper (v_dot2_f32_f16) ----------------
__device__ __forceinline__ float dot2f(u32 w, u32 h, float acc) {
#if __has_builtin(__builtin_amdgcn_fdot2)
    return __builtin_amdgcn_fdot2(__builtin_bit_cast(h2v, w),
                                  __builtin_bit_cast(h2v, h), acc, false);
#else
    __half2 a = __builtin_bit_cast(__half2, w);
    __half2 b = __builtin_bit_cast(__half2, h);
    return acc + __low2float(a) * __low2float(b) + __high2float(a) * __high2float(b);
#endif
}

__device__ __forceinline__ u32 pkf16(float a, float b) {
    __half2 h = __floats2half2_rn(a, b);
    return __builtin_bit_cast(u32, h);
}

// Pair-reduce stage via DPP (exact xor for quad_perm ctrls).
// keep = bit? b : a; give = bit? a : b; return keep + partner's give.
// Partner (lane^d) computed give with the opposite bit -> it donates exactly
// the acc this lane keeps. After all stages lane holds acc[sub] fully summed.
template <int CTRL>
__device__ __forceinline__ float prs_dpp(float a, float b, bool bit) {
    float keep = bit ? b : a;
    float give = bit ? a : b;
    int gv = __builtin_bit_cast(int, give);
    float got = __builtin_bit_cast(float,
        __builtin_amdgcn_update_dpp(0, gv, CTRL, 0xF, 0xF, true));
    return keep + got;
}
__device__ __forceinline__ float prs_shfl4(float a, float b, bool bit) {
    float keep = bit ? b : a;
    float give = bit ? a : b;
    return keep + __shfl_xor(give, 4);
}

// ---------------- W_hh repack: fp32 -> per-thread fp16 layout ----------------
// Scan thread tid: g = tid>>3 owns outputs j = g*8+o (o=0..7), sub = tid&7 owns
// K-slice [sub*64, sub*64+64) (32 half2, k5 = cc*8+k, cc=0..3, k=0..7).
// Registers (224 u32/thread): r = o*32 + k5 for o=0..6.
// LDS (32 u32/thread, 64KB): o=7, chunks c=0..7 of [512][4] u32, k5 = c*4+q.
__global__ void prep_w(const float* __restrict__ Whh, u32* __restrict__ wreg,
                       u32* __restrict__ wlds) {
    const int tid = threadIdx.x;
    const int g = tid >> 3, sub = tid & 7;
    const int bid = blockIdx.x;
    if (bid < 224) {
        const int r = bid, o = r >> 5, k5 = r & 31;
        const int j = g * 8 + o, i = sub * 64 + 2 * k5;
        wreg[r * 512 + tid] = pkf16(Whh[j * H_ + i], Whh[j * H_ + i + 1]);
    } else {
        const int c = bid - 224;            // 0..7
        const int j = g * 8 + 7;
        for (int q = 0; q < 4; q++) {
            const int k5 = c * 4 + q;
            const int i = sub * 64 + 2 * k5;
            wlds[c * 2048 + tid * 4 + q] = pkf16(Whh[j * H_ + i], Whh[j * H_ + i + 1]);
        }
    }
}

// ---------------- Phase 1: Xp = X @ W_ih^T + (b_ih + b_hh), into d_out ----------------
#define BM 128
#define BN 64

__launch_bounds__(256, 3)
__global__ void gemm_xp(const float* __restrict__ X, const float* __restrict__ Wih,
                        const float* __restrict__ bih, const float* __restrict__ bhh,
                        float* __restrict__ out) {
    __shared__ u32 Xs[16][BM + 4];   // half2 entries, k2-major (k2 = k/2)
    __shared__ u32 Ws[16][BN + 4];
    const int t = threadIdx.x;
    const int bn = blockIdx.x & 7;
    const int bm = blockIdx.x >> 3;
    const int m0 = bm * BM, n0 = bn * BN;
    const int tm = t & 15, tn = t >> 4;
    float acc[8][4];
#pragma unroll
    for (int i = 0; i < 8; i++)
#pragma unroll
        for (int j = 0; j < 4; j++) acc[i][j] = 0.f;
    const int kc = t & 7, rr = t >> 3;
    const int key = ((tm >> 2) & 1) << 2;     // XOR spread (bijective)
    for (int kt = 0; kt < 16; kt++) {
        const int k0 = kt * 32;
#pragma unroll
        for (int it = 0; it < 4; it++) {
            const int m = it * 32 + rr;
            float4 v = *(const float4*)&X[(size_t)(m0 + m) * I_ + k0 + kc * 4];
            const int mp = m ^ (((m >> 5) & 1) << 2);
            Xs[kc * 2 + 0][mp] = pkf16(v.x, v.y);
            Xs[kc * 2 + 1][mp] = pkf16(v.z, v.w);
        }
#pragma unroll
        for (int it = 0; it < 2; it++) {
            const int n = it * 32 + rr;
            float4 v = *(const float4*)&Wih[(size_t)(n0 + n) * I_ + k0 + kc * 4];
            Ws[kc * 2 + 0][n] = pkf16(v.x, v.y);
            Ws[kc * 2 + 1][n] = pkf16(v.z, v.w);
        }
        __syncthreads();
#pragma unroll
        for (int k2 = 0; k2 < 16; k2++) {
            uint4 a0 = *(const uint4*)&Xs[k2][(tm * 8) ^ key];
            uint4 a1 = *(const uint4*)&Xs[k2][(tm * 8 + 4) ^ key];
            uint4 bv = *(const uint4*)&Ws[k2][tn * 4];
            u32 aa[8] = {a0.x, a0.y, a0.z, a0.w, a1.x, a1.y, a1.z, a1.w};
            u32 bb[4] = {bv.x, bv.y, bv.z, bv.w};
#pragma unroll
            for (int mi = 0; mi < 8; mi++)
#pragma unroll
                for (int ni = 0; ni < 4; ni++)
                    acc[mi][ni] = dot2f(aa[mi], bb[ni], acc[mi][ni]);
        }
        __syncthreads();
    }
    float4 b1 = *(const float4*)&bih[n0 + tn * 4];
    float4 b2 = *(const float4*)&bhh[n0 + tn * 4];
    float4 bs = {b1.x + b2.x, b1.y + b2.y, b1.z + b2.z, b1.w + b2.w};
#pragma unroll
    for (int mi = 0; mi < 8; mi++) {
        const int row = m0 + tm * 8 + mi;
        float4 st = {acc[mi][0] + bs.x, acc[mi][1] + bs.y,
                     acc[mi][2] + bs.z, acc[mi][3] + bs.w};
        *(float4*)&out[(size_t)row * H_ + n0 + tn * 4] = st;
    }
}

// ---------------- Phase 2: sequential scan, one block per batch element ----------------
// 512 threads. W_hh fp16: 224 u32/thread in regs (o=0..6) + 32 u32 in LDS (o=7, 64KB).
// h broadcast via XOR-swizzled half2 LDS, ping-pong -> 1 raw barrier/step.
// Butterfly pair-reduce: DPP xor1/xor2 + shfl xor4; lane ends with its own acc[sub].

#define STEP_K(k, hval)                                         \
    acc0 = dot2f(w2[0 * 32 + cc * 8 + k], (hval), acc0);        \
    acc1 = dot2f(w2[1 * 32 + cc * 8 + k], (hval), acc1);        \
    acc2 = dot2f(w2[2 * 32 + cc * 8 + k], (hval), acc2);        \
    acc3 = dot2f(w2[3 * 32 + cc * 8 + k], (hval), acc3);        \
    acc4 = dot2f(w2[4 * 32 + cc * 8 + k], (hval), acc4);        \
    acc5 = dot2f(w2[5 * 32 + cc * 8 + k], (hval), acc5);        \
    acc6 = dot2f(w2[6 * 32 + cc * 8 + k], (hval), acc6);

__launch_bounds__(512)
__attribute__((amdgpu_waves_per_eu(2, 2)))
__global__ void rnn_scan(const u32* __restrict__ wreg, const u32* __restrict__ wlds_g,
                         float* __restrict__ out) {
    __shared__ u32 wl[16384];   // 64 KB: o=7 chunks
    __shared__ u32 hh[512];     // 2 x 256 half2 (ping-pong)
    const int tid = threadIdx.x;
    const int sub = tid & 7;
    u32 w2[224];
#pragma unroll
    for (int r = 0; r < 224; r++) w2[r] = wreg[r * 512 + tid];
#pragma unroll
    for (int i = 0; i < 32; i++) wl[i * 512 + tid] = wlds_g[i * 512 + tid];
    hh[tid] = 0u;               // h0 = 0 (both buffers zeroed)
    __syncthreads();
    float* p = out + (size_t)blockIdx.x * (T_ * H_) + tid;  // xp load / h store ptr
    const int xorkey = sub << 2;
    __half* hhh = reinterpret_cast<__half*>(hh);
    const int wv = tid >> 1;
    const int wslot = (wv ^ (((wv >> 5) & 7) << 2)) * 2 + (tid & 1);
    const int wbase = tid << 2;
    const bool b0 = (sub & 1) != 0, b1 = (sub & 2) != 0, b2 = (sub & 4) != 0;
    for (int t = 0; t < T_; t++) {
        const float xp = *p;            // issued right after barrier, used at tail
        const int rb = (t & 1) << 8;
        float acc0 = 0.f, acc1 = 0.f, acc2 = 0.f, acc3 = 0.f;
        float acc4 = 0.f, acc5 = 0.f, acc6 = 0.f, acc7 = 0.f;
#pragma unroll
        for (int cc = 0; cc < 4; cc++) {
            uint4 hA = *(const uint4*)&hh[rb + ((sub * 32 + cc * 8) ^ xorkey)];
            uint4 w7a = *(const uint4*)&wl[(cc * 2) * 2048 + wbase];
            STEP_K(0, hA.x); acc7 = dot2f(w7a.x, hA.x, acc7);
            STEP_K(1, hA.y); acc7 = dot2f(w7a.y, hA.y, acc7);
            STEP_K(2, hA.z); acc7 = dot2f(w7a.z, hA.z, acc7);
            STEP_K(3, hA.w); acc7 = dot2f(w7a.w, hA.w, acc7);
            uint4 hB = *(const uint4*)&hh[rb + ((sub * 32 + cc * 8 + 4) ^ xorkey)];
            uint4 w7b = *(const uint4*)&wl[(cc * 2 + 1) * 2048 + wbase];
            STEP_K(4, hB.x); acc7 = dot2f(w7b.x, hB.x, acc7);
            STEP_K(5, hB.y); acc7 = dot2f(w7b.y, hB.y, acc7);
            STEP_K(6, hB.z); acc7 = dot2f(w7b.z, hB.z, acc7);
            STEP_K(7, hB.w); acc7 = dot2f(w7b.w, hB.w, acc7);
        }
        // butterfly pair-reduce over the 8 sub-lanes; lane keeps its acc[sub]
        float s0 = prs_dpp<0xB1>(acc0, acc1, b0);
        float s2 = prs_dpp<0xB1>(acc2, acc3, b0);
        float s4 = prs_dpp<0xB1>(acc4, acc5, b0);
        float s6 = prs_dpp<0xB1>(acc6, acc7, b0);
        float u0 = prs_dpp<0x4E>(s0, s2, b1);
        float u4 = prs_dpp<0x4E>(s4, s6, b1);
        float r  = prs_shfl4(u0, u4, b2);
        const float pre = xp + r;
        const float e = __expf(-2.f * fabsf(pre));
        const float th = __builtin_copysignf((1.f - e) / (1.f + e), pre);
        *p = th;                        // overwrite Xp[b,t,tid] with h_t
        p += H_;
        hhh[(((t & 1) ^ 1) << 9) + wslot] = __float2half(th);
        asm volatile("s_waitcnt lgkmcnt(0)" ::: "memory");
        __builtin_amdgcn_sched_barrier(0);
        __builtin_amdgcn_s_barrier();
        __builtin_amdgcn_sched_barrier(0);
    }
}

extern "C" void kernel_launch(void* const* d_in, const int* in_sizes, int n_in,
                              void* d_out, int out_size, void* d_ws, size_t ws_size,
                              hipStream_t stream) {
    const float* X    = (const float*)d_in[0];
    const float* Wih  = (const float*)d_in[1];
    const float* Whh  = (const float*)d_in[2];
    const float* bih  = (const float*)d_in[3];
    const float* bhh  = (const float*)d_in[4];
    float* out = (float*)d_out;
    // workspace: 114688 dwords wreg + 16384 dwords wlds = 512 KB
    u32* wreg = (u32*)d_ws;
    u32* wlds = wreg + 114688;

    prep_w<<<dim3(232), dim3(512), 0, stream>>>(Whh, wreg, wlds);
    gemm_xp<<<dim3((65536 / BM) * (H_ / BN)), dim3(256), 0, stream>>>(X, Wih, bih, bhh, out);
    rnn_scan<<<dim3(B_), dim3(512), 0, stream>>>(wreg, wlds, out);
}